// Round 2
// baseline (165.046 us; speedup 1.0000x reference)
//
#include <hip/hip_runtime.h>

// Row-wise top-K(32) of relu(A), zero elsewhere. N=8192 fp32 per row.
// One 512-thread block per row. Radix-select via 2048-bin histogram of the
// float bit pattern (bits>>20: exponent + 3 mantissa bits — monotonic for
// positive floats). Exact tie-break (value desc, col asc) resolved on the
// cutoff bin BEFORE the output pass, so the final write is one coalesced
// burst with no trailing barrier/patch.

constexpr int N     = 8192;
constexpr int K     = 32;
constexpr int NBINS = 2048;     // positive fp32: bits>>20 in [0, 2048)
constexpr int CAP   = 256;      // cutoff-bin candidates (expected ~24)
constexpr int BLOCK = 512;
constexpr int SLOTS = CAP / 64;

__global__ __launch_bounds__(BLOCK, 8)
void topk_relu_kernel(const float* __restrict__ A, float* __restrict__ Out) {
    const int row  = blockIdx.x;
    const int tid  = threadIdx.x;
    const int lane = tid & 63;

    __shared__ unsigned hist[NBINS];
    __shared__ float    cand_val[CAP];
    __shared__ int      cand_col[CAP];
    __shared__ unsigned cand_cnt;

    #pragma unroll
    for (int i = 0; i < NBINS / BLOCK; ++i) hist[tid + i * BLOCK] = 0u;
    if (tid == 0) cand_cnt = 0u;
    __syncthreads();

    // ---- pass 1: load row to registers (coalesced), histogram positives ----
    const float4* __restrict__ Arow = reinterpret_cast<const float4*>(A + (size_t)row * N);
    float4 vf[4];
    #pragma unroll
    for (int i = 0; i < 4; ++i) vf[i] = Arow[i * BLOCK + tid];

    #pragma unroll
    for (int i = 0; i < 4; ++i) {
        { float f = vf[i].x; if (f > 0.0f) atomicAdd(&hist[__float_as_uint(f) >> 20], 1u); }
        { float f = vf[i].y; if (f > 0.0f) atomicAdd(&hist[__float_as_uint(f) >> 20], 1u); }
        { float f = vf[i].z; if (f > 0.0f) atomicAdd(&hist[__float_as_uint(f) >> 20], 1u); }
        { float f = vf[i].w; if (f > 0.0f) atomicAdd(&hist[__float_as_uint(f) >> 20], 1u); }
    }
    __syncthreads();

    // ---- pass 2: ALL waves redundantly find cutoff bin B, G = count above B ----
    // lane l owns bins [l*32, l*32+32); staggered read -> 2 lanes/bank (free).
    int B, G;
    {
        unsigned s = 0;
        #pragma unroll
        for (int i = 0; i < 32; ++i) s += hist[lane * 32 + ((i + lane) & 31)];
        unsigned acc = s;                       // suffix sum over lanes
        #pragma unroll
        for (int off = 1; off < 64; off <<= 1) {
            unsigned t = __shfl_down(acc, off, 64);
            if (lane + off < 64) acc += t;
        }
        unsigned long long m = __ballot(acc >= (unsigned)K);
        if (m == 0ull) {                        // < K positives: keep them all
            B = -1; G = 0;
        } else {
            int g = 63 - __clzll((long long)m); // highest group with suffix >= K
            unsigned above = (g < 63) ? (unsigned)__shfl((int)acc, g + 1, 64) : 0u;
            unsigned h  = (lane < 32) ? hist[g * 32 + lane] : 0u;
            unsigned a2 = h;                    // within-group suffix
            #pragma unroll
            for (int off = 1; off < 64; off <<= 1) {
                unsigned t = __shfl_down(a2, off, 64);
                if (lane + off < 64) a2 += t;
            }
            unsigned long long m2 = __ballot(above + a2 >= (unsigned)K);
            int bl = 63 - __clzll((long long)m2);
            B = g * 32 + bl;
            G = (int)(above + (unsigned)__shfl((int)a2, bl, 64)
                            - (unsigned)__shfl((int)h,  bl, 64));
        }
    }
    const int R = K - G;                        // how many of bin B to keep

    // ---- pass 3: gather cutoff-bin candidates from registers ----
    if (B >= 0) {
        #pragma unroll
        for (int i = 0; i < 4; ++i) {
            const int colbase = (i * BLOCK + tid) * 4;
            #define COLL(FF, CC) { float f = (FF);                                  \
                if (f > 0.0f && (int)(__float_as_uint(f) >> 20) == B) {             \
                    unsigned ix = atomicAdd(&cand_cnt, 1u);                         \
                    if (ix < CAP) { cand_val[ix] = f; cand_col[ix] = (CC); } } }
            COLL(vf[i].x, colbase + 0)
            COLL(vf[i].y, colbase + 1)
            COLL(vf[i].z, colbase + 2)
            COLL(vf[i].w, colbase + 3)
            #undef COLL
        }
    }
    __syncthreads();

    // ---- pass 4: ALL waves redundantly find the rank-R boundary (vR, cR) ----
    // keep rule for bin B: (f > vR) || (f == vR && col <= cR)
    float vR = __int_as_float(0x7f800000);      // +inf sentinel: keep none
    int   cR = -1;
    {
        const int C = (int)min(cand_cnt, (unsigned)CAP);
        if (B >= 0 && R > 0 && C > 0) {
            float mv[SLOTS]; int mc[SLOTS]; int rk[SLOTS];
            #pragma unroll
            for (int s = 0; s < SLOTS; ++s) {
                const int j = lane + s * 64;
                if (j < C) { mv[s] = cand_val[j]; mc[s] = cand_col[j]; }
                else       { mv[s] = -1.0f;       mc[s] = 0x7fffffff; }
                rk[s] = 0;
            }
            for (int j = 0; j < C; ++j) {       // LDS broadcast reads (free)
                const float vj = cand_val[j];
                const int   cj = cand_col[j];
                #pragma unroll
                for (int s = 0; s < SLOTS; ++s)
                    if (vj > mv[s] || (vj == mv[s] && cj < mc[s])) rk[s]++;
            }
            float bv = 0.0f; int bc = -1; bool found = false;
            #pragma unroll
            for (int s = 0; s < SLOTS; ++s)
                if (lane + s * 64 < C && rk[s] == R - 1) { bv = mv[s]; bc = mc[s]; found = true; }
            unsigned long long bm = __ballot(found);
            if (bm != 0ull) {
                int src = (int)__ffsll((long long)bm) - 1;
                vR = __shfl(bv, src, 64);
                cR = __shfl(bc, src, 64);
            }
        }
    }

    // ---- pass 5: single coalesced output burst (kernel ends, no barrier) ----
    float* __restrict__ Orow = Out + (size_t)row * N;
    #pragma unroll
    for (int i = 0; i < 4; ++i) {
        float4 w;
        const int colbase = (i * BLOCK + tid) * 4;
        #define EMIT(FF, CC, WW) { float f = (FF); float o = 0.0f;                   \
            if (f > 0.0f) { int b = (int)(__float_as_uint(f) >> 20);                 \
                if (b > B || (b == B && (f > vR || (f == vR && (CC) <= cR)))) o = f; } \
            (WW) = o; }
        EMIT(vf[i].x, colbase + 0, w.x)
        EMIT(vf[i].y, colbase + 1, w.y)
        EMIT(vf[i].z, colbase + 2, w.z)
        EMIT(vf[i].w, colbase + 3, w.w)
        #undef EMIT
        reinterpret_cast<float4*>(Orow)[i * BLOCK + tid] = w;
    }
}

extern "C" void kernel_launch(void* const* d_in, const int* in_sizes, int n_in,
                              void* d_out, int out_size, void* d_ws, size_t ws_size,
                              hipStream_t stream) {
    const float* A   = (const float*)d_in[0];
    float*       Out = (float*)d_out;
    (void)in_sizes; (void)n_in; (void)d_ws; (void)ws_size; (void)out_size;
    topk_relu_kernel<<<dim3(N), dim3(BLOCK), 0, stream>>>(A, Out);
}

// Round 3
// 115.499 us; speedup vs baseline: 1.4290x; 1.4290x over previous
//
#include <hip/hip_runtime.h>

// Row-wise top-K(32) of relu(A), zero elsewhere. N=8192 fp32 per row.
// One 256-thread block per row, row held in registers (8x float4/thread).
// Radix-select via 2048-bin histogram of the float bit pattern (bits>>20:
// exponent + 3 mantissa bits — monotonic for positive floats). The exact
// (value desc, col asc) rank-R boundary of the cutoff bin is computed BEFORE
// the output pass, so the final write is one coalesced burst with no
// trailing barrier / patch stores.
//
// R1 lesson: do NOT force min-waves in __launch_bounds__ — capping VGPRs
// makes the compiler re-load the row from global instead of holding it
// (VGPR_Count dropped to 24, VALUBusy 62%, 165 us). Let it hold 32 VGPRs.

constexpr int N     = 8192;
constexpr int K     = 32;
constexpr int NBINS = 2048;     // positive fp32: bits>>20 in [0, 2048)
constexpr int CAP   = 256;      // cutoff-bin candidates (expected ~5)
constexpr int BLOCK = 256;
constexpr int SLOTS = CAP / 64;

__global__ __launch_bounds__(BLOCK)
void topk_relu_kernel(const float* __restrict__ A, float* __restrict__ Out) {
    const int row  = blockIdx.x;
    const int tid  = threadIdx.x;
    const int lane = tid & 63;

    __shared__ unsigned hist[NBINS];
    __shared__ float    cand_val[CAP];
    __shared__ int      cand_col[CAP];
    __shared__ unsigned cand_cnt;

    #pragma unroll
    for (int i = 0; i < NBINS / BLOCK; ++i) hist[tid + i * BLOCK] = 0u;
    if (tid == 0) cand_cnt = 0u;
    __syncthreads();

    // ---- pass 1: load row to registers (coalesced), histogram positives ----
    const float4* __restrict__ Arow = reinterpret_cast<const float4*>(A + (size_t)row * N);
    float4 vf[8];
    #pragma unroll
    for (int i = 0; i < 8; ++i) vf[i] = Arow[i * BLOCK + tid];

    #pragma unroll
    for (int i = 0; i < 8; ++i) {
        { float f = vf[i].x; if (f > 0.0f) atomicAdd(&hist[__float_as_uint(f) >> 20], 1u); }
        { float f = vf[i].y; if (f > 0.0f) atomicAdd(&hist[__float_as_uint(f) >> 20], 1u); }
        { float f = vf[i].z; if (f > 0.0f) atomicAdd(&hist[__float_as_uint(f) >> 20], 1u); }
        { float f = vf[i].w; if (f > 0.0f) atomicAdd(&hist[__float_as_uint(f) >> 20], 1u); }
    }
    __syncthreads();

    // ---- pass 2: ALL waves redundantly find cutoff bin B, G = count above B ----
    // lane l owns bins [l*32, l*32+32); staggered read -> 2 lanes/bank (free).
    int B, G;
    {
        unsigned s = 0;
        #pragma unroll
        for (int i = 0; i < 32; ++i) s += hist[lane * 32 + ((i + lane) & 31)];
        unsigned acc = s;                       // suffix sum over lanes
        #pragma unroll
        for (int off = 1; off < 64; off <<= 1) {
            unsigned t = __shfl_down(acc, off, 64);
            if (lane + off < 64) acc += t;
        }
        unsigned long long m = __ballot(acc >= (unsigned)K);
        if (m == 0ull) {                        // < K positives: keep them all
            B = -1; G = 0;
        } else {
            int g = 63 - __clzll((long long)m); // highest group with suffix >= K
            unsigned above = (g < 63) ? (unsigned)__shfl((int)acc, g + 1, 64) : 0u;
            unsigned h  = (lane < 32) ? hist[g * 32 + lane] : 0u;
            unsigned a2 = h;                    // within-group suffix
            #pragma unroll
            for (int off = 1; off < 64; off <<= 1) {
                unsigned t = __shfl_down(a2, off, 64);
                if (lane + off < 64) a2 += t;
            }
            unsigned long long m2 = __ballot(above + a2 >= (unsigned)K);
            int bl = 63 - __clzll((long long)m2);
            B = g * 32 + bl;
            G = (int)(above + (unsigned)__shfl((int)a2, bl, 64)
                            - (unsigned)__shfl((int)h,  bl, 64));
        }
    }
    const int R = K - G;                        // how many of bin B to keep

    // ---- pass 3: gather cutoff-bin candidates from registers ----
    if (B >= 0) {
        #pragma unroll
        for (int i = 0; i < 8; ++i) {
            const int colbase = (i * BLOCK + tid) * 4;
            #define COLL(FF, CC) { float f = (FF);                                  \
                if (f > 0.0f && (int)(__float_as_uint(f) >> 20) == B) {             \
                    unsigned ix = atomicAdd(&cand_cnt, 1u);                         \
                    if (ix < CAP) { cand_val[ix] = f; cand_col[ix] = (CC); } } }
            COLL(vf[i].x, colbase + 0)
            COLL(vf[i].y, colbase + 1)
            COLL(vf[i].z, colbase + 2)
            COLL(vf[i].w, colbase + 3)
            #undef COLL
        }
    }
    __syncthreads();

    // ---- pass 4: ALL waves redundantly find the rank-R boundary (vR, cR) ----
    // keep rule for bin B: (f > vR) || (f == vR && col <= cR)
    float vR = __int_as_float(0x7f800000);      // +inf sentinel: keep none
    int   cR = -1;
    {
        const int C = (int)min(cand_cnt, (unsigned)CAP);
        if (B >= 0 && R > 0 && C > 0) {
            float mv[SLOTS]; int mc[SLOTS]; int rk[SLOTS];
            #pragma unroll
            for (int s = 0; s < SLOTS; ++s) {
                const int j = lane + s * 64;
                if (j < C) { mv[s] = cand_val[j]; mc[s] = cand_col[j]; }
                else       { mv[s] = -1.0f;       mc[s] = 0x7fffffff; }
                rk[s] = 0;
            }
            for (int j = 0; j < C; ++j) {       // LDS broadcast reads (free)
                const float vj = cand_val[j];
                const int   cj = cand_col[j];
                #pragma unroll
                for (int s = 0; s < SLOTS; ++s)
                    if (vj > mv[s] || (vj == mv[s] && cj < mc[s])) rk[s]++;
            }
            float bv = 0.0f; int bc = -1; bool found = false;
            #pragma unroll
            for (int s = 0; s < SLOTS; ++s)
                if (lane + s * 64 < C && rk[s] == R - 1) { bv = mv[s]; bc = mc[s]; found = true; }
            unsigned long long bm = __ballot(found);
            if (bm != 0ull) {
                int src = (int)__ffsll((long long)bm) - 1;
                vR = __shfl(bv, src, 64);
                cR = __shfl(bc, src, 64);
            }
        }
    }

    // ---- pass 5: single coalesced output burst (kernel ends, no barrier) ----
    float* __restrict__ Orow = Out + (size_t)row * N;
    #pragma unroll
    for (int i = 0; i < 8; ++i) {
        float4 w;
        const int colbase = (i * BLOCK + tid) * 4;
        #define EMIT(FF, CC, WW) { float f = (FF); float o = 0.0f;                   \
            if (f > 0.0f) { int b = (int)(__float_as_uint(f) >> 20);                 \
                if (b > B || (b == B && (f > vR || (f == vR && (CC) <= cR)))) o = f; } \
            (WW) = o; }
        EMIT(vf[i].x, colbase + 0, w.x)
        EMIT(vf[i].y, colbase + 1, w.y)
        EMIT(vf[i].z, colbase + 2, w.z)
        EMIT(vf[i].w, colbase + 3, w.w)
        #undef EMIT
        reinterpret_cast<float4*>(Orow)[i * BLOCK + tid] = w;
    }
}

extern "C" void kernel_launch(void* const* d_in, const int* in_sizes, int n_in,
                              void* d_out, int out_size, void* d_ws, size_t ws_size,
                              hipStream_t stream) {
    const float* A   = (const float*)d_in[0];
    float*       Out = (float*)d_out;
    (void)in_sizes; (void)n_in; (void)d_ws; (void)ws_size; (void)out_size;
    topk_relu_kernel<<<dim3(N), dim3(BLOCK), 0, stream>>>(A, Out);
}

// Round 4
// 92.244 us; speedup vs baseline: 1.7892x; 1.2521x over previous
//
#include <hip/hip_runtime.h>

// Row-wise top-K(32) of relu(A), zero elsewhere. N=8192 fp32 per row.
// One 256-thread block per row, row held in registers (8x float4/thread).
// Radix-select via histogram of the float bit pattern (bits>>20: exponent +
// 3 mantissa bits — monotonic for positive floats). Speculative mode only
// histograms values > 2.0 (expected ~186/row; top-32 of N(0,1)x8192 are all
// > 3) into bins [1024,2048); exact block-uniform fallback to a full
// histogram if a row has < K survivors. The exact (value desc, col asc)
// rank-K boundary (vR,cR) is computed before the output pass, so the final
// write is one coalesced NON-TEMPORAL burst (nt: don't churn A out of L3).
//
// R1 lesson: do NOT force min-waves in __launch_bounds__ — capping VGPRs
// makes the compiler re-load the row from global instead of holding it.

constexpr int N     = 8192;
constexpr int K     = 32;
constexpr int NBINS = 2048;     // positive fp32: bits>>20 in [0, 2048)
constexpr int CAP   = 256;      // cutoff-bin candidates (expected ~5-15)
constexpr int BLOCK = 256;
constexpr int SLOTS = CAP / 64;
constexpr float TSPEC     = 2.0f;  // speculative threshold; bin(2.0) = 1024
constexpr int   SPEC_BASE = 1024;  // values > 2.0 land in bins [1024, 2048)

typedef float f4 __attribute__((ext_vector_type(4)));

// Find cutoff bin B (rank-K bin) and G = count strictly above B, from
// hist[base .. base + 64*PER). All waves compute identical results.
template<int PER>
__device__ __forceinline__ bool find_cutoff(const unsigned* hist, int lane,
                                            int base, int& B, int& G) {
    unsigned s = 0;
    #pragma unroll
    for (int i = 0; i < PER; ++i)
        s += hist[base + lane * PER + ((i + lane) & (PER - 1))];  // staggered
    unsigned acc = s;                       // inclusive suffix sum over lanes
    #pragma unroll
    for (int off = 1; off < 64; off <<= 1) {
        unsigned t = __shfl_down(acc, off, 64);
        if (lane + off < 64) acc += t;
    }
    unsigned long long m = __ballot(acc >= (unsigned)K);
    if (m == 0ull) return false;
    int g = 63 - __clzll((long long)m);     // highest group with suffix >= K
    unsigned above = (g < 63) ? (unsigned)__shfl((int)acc, g + 1, 64) : 0u;
    unsigned h  = (lane < PER) ? hist[base + g * PER + lane] : 0u;
    unsigned a2 = h;                        // within-group suffix
    #pragma unroll
    for (int off = 1; off < 64; off <<= 1) {
        unsigned t = __shfl_down(a2, off, 64);
        if (lane + off < 64) a2 += t;
    }
    unsigned long long m2 = __ballot(above + a2 >= (unsigned)K);
    int bl = 63 - __clzll((long long)m2);
    B = base + g * PER + bl;
    G = (int)(above + (unsigned)__shfl((int)a2, bl, 64)
                    - (unsigned)__shfl((int)h,  bl, 64));
    return true;
}

__global__ __launch_bounds__(BLOCK)
void topk_relu_kernel(const float* __restrict__ A, float* __restrict__ Out) {
    const int row  = blockIdx.x;
    const int tid  = threadIdx.x;
    const int lane = tid & 63;

    __shared__ unsigned hist[NBINS];
    __shared__ float    cand_val[CAP];
    __shared__ int      cand_col[CAP];
    __shared__ unsigned cand_cnt;

    // zero only the speculative bins
    #pragma unroll
    for (int i = 0; i < (NBINS - SPEC_BASE) / BLOCK; ++i)
        hist[SPEC_BASE + tid + i * BLOCK] = 0u;
    if (tid == 0) cand_cnt = 0u;
    __syncthreads();

    // ---- pass 1: load row to registers; histogram only values > TSPEC ----
    const f4* __restrict__ Arow = reinterpret_cast<const f4*>(A + (size_t)row * N);
    f4 vf[8];
    #pragma unroll
    for (int i = 0; i < 8; ++i) vf[i] = Arow[i * BLOCK + tid];

    #pragma unroll
    for (int i = 0; i < 8; ++i) {
        #pragma unroll
        for (int c = 0; c < 4; ++c) {
            float f = vf[i][c];
            if (f > TSPEC) atomicAdd(&hist[__float_as_uint(f) >> 20], 1u);
        }
    }
    __syncthreads();

    // ---- pass 2: cutoff bin B, G = count above (all waves, redundant) ----
    int B, G;
    bool ok = find_cutoff<16>(hist, lane, SPEC_BASE, B, G);
    if (!ok) {
        // rare exact fallback: < K values above TSPEC in this row
        __syncthreads();                    // scan reads done before re-zero
        #pragma unroll
        for (int i = 0; i < NBINS / BLOCK; ++i) hist[tid + i * BLOCK] = 0u;
        __syncthreads();
        #pragma unroll
        for (int i = 0; i < 8; ++i) {
            #pragma unroll
            for (int c = 0; c < 4; ++c) {
                float f = vf[i][c];
                if (f > 0.0f) atomicAdd(&hist[__float_as_uint(f) >> 20], 1u);
            }
        }
        __syncthreads();
        if (!find_cutoff<32>(hist, lane, 0, B, G)) { B = -1; G = 0; }
    }
    const int R = K - G;                    // how many of bin B to keep (>=1)

    // ---- pass 3: gather cutoff-bin candidates from registers ----
    if (B >= 0) {
        #pragma unroll
        for (int i = 0; i < 8; ++i) {
            #pragma unroll
            for (int c = 0; c < 4; ++c) {
                float f = vf[i][c];
                if (f > 0.0f && (int)(__float_as_uint(f) >> 20) == B) {
                    unsigned ix = atomicAdd(&cand_cnt, 1u);
                    if (ix < CAP) {
                        cand_val[ix] = f;
                        cand_col[ix] = (i * BLOCK + tid) * 4 + c;
                    }
                }
            }
        }
    }
    __syncthreads();

    // ---- pass 4: rank-R boundary (vR, cR) of bin B (all waves, redundant) ----
    // final keep rule: f > vR || (f == vR && col <= cR)
    float vR = 0.0f;                        // B == -1 default: keep positives
    int   cR = -1;
    if (B >= 0) {
        vR = __int_as_float(0x7f800000);    // safety sentinel (unreachable)
        const int C = (int)min(cand_cnt, (unsigned)CAP);
        float mv[SLOTS]; int mc[SLOTS]; int rk[SLOTS];
        #pragma unroll
        for (int s = 0; s < SLOTS; ++s) {
            const int j = lane + s * 64;
            if (j < C) { mv[s] = cand_val[j]; mc[s] = cand_col[j]; }
            else       { mv[s] = -1.0f;       mc[s] = 0x7fffffff; }
            rk[s] = 0;
        }
        for (int j = 0; j < C; ++j) {       // LDS broadcast reads
            const float vj = cand_val[j];
            const int   cj = cand_col[j];
            #pragma unroll
            for (int s = 0; s < SLOTS; ++s)
                if (vj > mv[s] || (vj == mv[s] && cj < mc[s])) rk[s]++;
        }
        float bv = 0.0f; int bc = -1; bool found = false;
        #pragma unroll
        for (int s = 0; s < SLOTS; ++s)
            if (lane + s * 64 < C && rk[s] == R - 1) { bv = mv[s]; bc = mc[s]; found = true; }
        unsigned long long bm = __ballot(found);
        if (bm != 0ull) {
            int src = (int)__ffsll((long long)bm) - 1;
            vR = __shfl(bv, src, 64);
            cR = __shfl(bc, src, 64);
        }
    }

    // ---- pass 5: single coalesced NON-TEMPORAL output burst ----
    float* __restrict__ Orow = Out + (size_t)row * N;
    #pragma unroll
    for (int i = 0; i < 8; ++i) {
        f4 w;
        #pragma unroll
        for (int c = 0; c < 4; ++c) {
            float f   = vf[i][c];
            int   col = (i * BLOCK + tid) * 4 + c;
            bool keep = (f > vR) || (f == vR && col <= cR);
            w[c] = keep ? f : 0.0f;
        }
        __builtin_nontemporal_store(w, reinterpret_cast<f4*>(Orow) + i * BLOCK + tid);
    }
}

extern "C" void kernel_launch(void* const* d_in, const int* in_sizes, int n_in,
                              void* d_out, int out_size, void* d_ws, size_t ws_size,
                              hipStream_t stream) {
    const float* A   = (const float*)d_in[0];
    float*       Out = (float*)d_out;
    (void)in_sizes; (void)n_in; (void)d_ws; (void)ws_size; (void)out_size;
    topk_relu_kernel<<<dim3(N), dim3(BLOCK), 0, stream>>>(A, Out);
}